// Round 22
// baseline (105.190 us; speedup 1.0000x reference)
//
#include <hip/hip_runtime.h>

#define NB 256
#define NM 128
#define ND 64
#define NH 8

typedef float f32x4 __attribute__((ext_vector_type(4)));
typedef short bf16x8 __attribute__((ext_vector_type(8)));   // 8 bf16 = 4 VGPRs (16x16x32 A/B)
typedef short bf16x4 __attribute__((ext_vector_type(4)));   // 4 bf16 = 2 VGPRs
typedef unsigned short ushort_t;

__device__ __forceinline__ ushort_t f2bf(float f) {   // RNE f32->bf16 (prep kernel only)
    unsigned int x = __float_as_uint(f);
    x += 0x7fffu + ((x >> 16) & 1u);
    return (ushort_t)(x >> 16);
}

// v_cvt_pk_bf16_f32: 2 f32 -> 2 bf16 (RNE) in ONE VALU op (r19 win kept).
__device__ __forceinline__ unsigned cvtpk(float lo, float hi) {
    unsigned r;
    asm("v_cvt_pk_bf16_f32 %0, %1, %2" : "=v"(r) : "v"(lo), "v"(hi));
    return r;
}
__device__ __forceinline__ unsigned pk2(float a, float b) { return cvtpk(a, b); }
__device__ __forceinline__ bf16x4 pk4(float a, float b, float c, float d) {
    union { unsigned u[2]; bf16x4 v; } t;
    t.u[0] = cvtpk(a, b);
    t.u[1] = cvtpk(c, d);
    return t.v;
}
__device__ __forceinline__ bf16x8 pk8(float4 lo, float4 hi) {
    union { unsigned u[4]; bf16x8 v; } t;
    t.u[0] = cvtpk(lo.x, lo.y);
    t.u[1] = cvtpk(lo.z, lo.w);
    t.u[2] = cvtpk(hi.x, hi.y);
    t.u[3] = cvtpk(hi.z, hi.w);
    return t.v;
}

// XOR-swizzled LDS indices (T2), write and read via the SAME helper.
// XOR by multiples of 8 elems permutes 8-element blocks: b64 (4-elem aligned)
// and b128 (8-elem aligned) accesses both stay contiguous+aligned under it.
__device__ __forceinline__ int sw64(int row, int col)  { return row * 64  + (col ^ ((row & 7) << 3)); }
__device__ __forceinline__ int sw128(int row, int col) { return row * 128 + (col ^ ((row & 7) << 3)); }

__device__ __forceinline__ f32x4 MFMA(bf16x8 a, bf16x8 b, f32x4 c) {
    return __builtin_amdgcn_mfma_f32_16x16x32_bf16(a, b, c, 0, 0, 0);
}

// ============================================================================
// r22 KEY CHANGE: 16x16x16-equivalent MFMA via ZERO-PADDED 16x16x32 builtin.
// The _1k 16x16x16 builtin is NOT in the verified gfx950 intrinsic list, so
// the old __has_builtin-guarded path may have silently fallen back to an
// `asm volatile` with 2x s_nop 7 per call — volatile ordering forbids the
// scheduler from interleaving ANYTHING across the 48 calls/head/wave, which
// matches the zero-ILP signature in the counters (29K cy/head vs ~3-5K ideal).
// Identity: MFMA16(a,b,c) == MFMA32({a,0},{b,0},c): padding zeroes k=8g+4..7
// on BOTH operands, so the K=32 dot reduces to the same 16 k-slots with the
// same per-lane granule mapping (k=8g+r) and same f32x4 C/D layout.
// ============================================================================
__device__ __forceinline__ f32x4 MFMA16(bf16x4 a, bf16x4 b, f32x4 c) {
    union { bf16x4 h[2]; bf16x8 v; } ua, ub;
    ua.h[0] = a; ua.h[1] = (bf16x4)(short)0;
    ub.h[0] = b; ub.h[1] = (bf16x4)(short)0;
    return __builtin_amdgcn_mfma_f32_16x16x32_bf16(ua.v, ub.v, c, 0, 0, 0);
}

// ---- prep: transpose weights to bf16 fragment layout in d_ws ----
// ws (ushort): WqT[512][64] @0, WkT @32768, WvT @65536, WpT[64][512] @98304 (256 KB)
extern "C" __global__ void geat_prep(const float* __restrict__ Wq,
                                     const float* __restrict__ Wk,
                                     const float* __restrict__ Wv,
                                     const float* __restrict__ Wp,
                                     ushort_t* __restrict__ ws)
{
    int idx = blockIdx.x * 256 + threadIdx.x;   // 0..131071
    int seg = idx >> 15;
    int r = idx & 32767;
    float v;
    if      (seg == 0) v = Wq[(r & 63) * 512 + (r >> 6)];    // WqT[o][d] = Wq[d][o]
    else if (seg == 1) v = Wk[(r & 63) * 512 + (r >> 6)];
    else if (seg == 2) v = Wv[(r & 63) * 512 + (r >> 6)];
    else               v = Wp[(r & 511) * 64 + (r >> 9)];    // WpT[c][k] = Wp[k][c]
    ws[idx] = f2bf(v);
}

// ============================================================================
// Producer/consumer fused kernel — EXACT r21 chassis (100.0us, PASSED) with
// MFMA16 re-implemented as zero-padded MFMA32 builtin (see above). Everything
// else byte-identical.
// Grid 256 (1 block/CU), 768 thr = 12 waves = 3/SIMD guaranteed (r13: blocks
// never co-schedule; r12: 1024-thr -> 64-reg cap spills; VGPR law 65536/thr).
//  - waves 0..7  consumers: 16 rows each; per head: 2 b128 Q reads, fused
//    max-free S(MFMA32)->exp->PV, oproj. (r15: |s|<~6 so exp can't overflow;
//    masked = exact 0; normalize O~ once at the end.)
//  - waves 8..11 producers: K/V^T/Q of head h+1 (2 tiles of 16 rows).
// LDS 96 KB: 2 x {KB 8192, VTB 8192, QB 8192} ushorts. ONE barrier per head
// (h=NH-1 barrier dead -> skipped; h is block-uniform).
// DO NOT pass a >1 min-waves launch-bounds hint (r2/r5).
// ============================================================================
extern "C" __global__ __launch_bounds__(768, 1)
void geat_pc(const float* __restrict__ x, const int* __restrict__ edges,
             const float* __restrict__ bq, const float* __restrict__ bk,
             const float* __restrict__ bv, const float* __restrict__ ebias,
             const float* __restrict__ bp, const ushort_t* __restrict__ wt,
             float* __restrict__ out)
{
    __shared__ __align__(16) ushort_t sm[49152];  // 96 KB

    const int b    = blockIdx.x;
    const int tid  = threadIdx.x;
    const int w    = tid >> 6;          // wave 0..11
    const int lane = tid & 63;
    const int c    = lane & 15;
    const int g    = lane >> 4;
    const bool cons = (w < 8);
    const int mt   = cons ? (w * 16) : ((w - 8) * 32);   // consumer rows / producer base

    const ushort_t* WqT = wt;
    const ushort_t* WkT = wt + 32768;
    const ushort_t* WvT = wt + 65536;
    const ushort_t* WpT = wt + 98304;

    // ---- persistent per-role state ----
    unsigned epack[8];     // consumers: edge codes for row mt+c (n = 16nt+4g+r)
    bf16x8   pxA[2][2];    // producers: x frags for rows mt+16*tile+c
    if (cons) {
        const int* erow = edges + (size_t)b * NM * NM + (mt + c) * NM;
#pragma unroll
        for (int nt = 0; nt < 8; ++nt) {
            const int4 e4 = *(const int4*)&erow[nt * 16 + 4 * g];
            epack[nt] = (unsigned)(e4.x & 0xff) | ((unsigned)(e4.y & 0xff) << 8) |
                        ((unsigned)(e4.z & 0xff) << 16) | ((unsigned)(e4.w & 0xff) << 24);
        }
    } else {
#pragma unroll
        for (int tile = 0; tile < 2; ++tile) {
            const float* xb = x + (size_t)b * NM * ND + (mt + tile * 16 + c) * ND;
#pragma unroll
            for (int kt = 0; kt < 2; ++kt) {
                const float4 lo = *(const float4*)&xb[kt * 32 + 8 * g];
                const float4 hi = *(const float4*)&xb[kt * 32 + 8 * g + 4];
                pxA[tile][kt] = pk8(lo, hi);
            }
        }
    }

    f32x4 projacc[4];
#pragma unroll
    for (int i = 0; i < 4; ++i) projacc[i] = (f32x4)0.0f;

    // ---- producer: K + V^T + Q of head h2 into buf (32 rows: 2 tiles) ----
    auto PROJKVQ = [&](int h2, ushort_t* buf) {
        ushort_t* KBn = buf;
        ushort_t* VTn = buf + 8192;
        ushort_t* QBn = buf + 16384;
#pragma unroll
        for (int dt = 0; dt < 4; ++dt) {
            const int d0 = dt * 16;
            bf16x8 wqf[2], wkf[2], wvf[2];
#pragma unroll
            for (int kt = 0; kt < 2; ++kt) {
                const int woff = (h2 * 64 + d0 + c) * 64 + kt * 32 + 8 * g;
                wqf[kt] = *(const bf16x8*)&WqT[woff];
                wkf[kt] = *(const bf16x8*)&WkT[woff];
                wvf[kt] = *(const bf16x8*)&WvT[woff];
            }
            const float4 bqv = *(const float4*)&bq[h2 * 64 + d0 + 4 * g];
            const float4 bkv = *(const float4*)&bk[h2 * 64 + d0 + 4 * g];
            const float  bvv = bv[h2 * 64 + d0 + c];
#pragma unroll
            for (int tile = 0; tile < 2; ++tile) {
                f32x4 qT = (f32x4)0.0f, kT = (f32x4)0.0f, vn = (f32x4)0.0f;
#pragma unroll
                for (int kt = 0; kt < 2; ++kt) {
                    qT = MFMA(wqf[kt], pxA[tile][kt], qT);   // D: Q[row+c][d0+4g+r]
                    kT = MFMA(wkf[kt], pxA[tile][kt], kT);   // D: K[row+c][d0+4g+r]
                    vn = MFMA(pxA[tile][kt], wvf[kt], vn);   // D: V[row+4g+r][d0+c]
                }
                const int rowb = mt + tile * 16;
                uint2 qp, kp, vp;
                qp.x = pk2(qT[0] + bqv.x, qT[1] + bqv.y);
                qp.y = pk2(qT[2] + bqv.z, qT[3] + bqv.w);
                kp.x = pk2(kT[0] + bkv.x, kT[1] + bkv.y);
                kp.y = pk2(kT[2] + bkv.z, kT[3] + bkv.w);
                vp.x = pk2(vn[0] + bvv, vn[1] + bvv);
                vp.y = pk2(vn[2] + bvv, vn[3] + bvv);
                *(uint2*)&QBn[sw64(rowb + c, d0 + 4 * g)] = qp;
                *(uint2*)&KBn[sw64(rowb + c, d0 + 4 * g)] = kp;
                *(uint2*)&VTn[sw128(d0 + c, rowb + 4 * g)] = vp;
            }
        }
    };

    // ---- prologue: producers fill buffer 0 with head 0's K/V^T/Q ----
    if (!cons) PROJKVQ(0, sm);
    __syncthreads();

#pragma unroll 1
    for (int h = 0; h < NH; ++h) {
        ushort_t* bufc = sm + (h & 1) * 24576;
        ushort_t* bufn = sm + ((h & 1) ^ 1) * 24576;

        if (cons) {
            ushort_t* KBc = bufc;
            ushort_t* VTc = bufc + 8192;
            ushort_t* QBc = bufc + 16384;

            // ---- own-row Q granules as two b128 reads (k = kt*32 + 8g + j) ----
            bf16x8 qcur8[2];
#pragma unroll
            for (int kt = 0; kt < 2; ++kt)
                qcur8[kt] = *(const bf16x8*)&QBc[sw64(mt + c, kt * 32 + 8 * g)];

            const float eb0 = ebias[0 * NH + h], eb1 = ebias[1 * NH + h], eb2 = ebias[2 * NH + h];
            const float eb3 = ebias[3 * NH + h], eb4 = ebias[4 * NH + h];

            // ---- fused max-free S(MFMA32) -> exp -> PV, one n-tile at a time ----
            f32x4 ot[4];
#pragma unroll
            for (int dt = 0; dt < 4; ++dt) ot[dt] = (f32x4)0.0f;
            float sum = 0.f;
#pragma unroll
            for (int nt = 0; nt < 8; ++nt) {
                const int n0 = nt * 16;
                f32x4 acc = (f32x4)0.0f;
#pragma unroll
                for (int kt = 0; kt < 2; ++kt) {
                    const bf16x8 kgr = *(const bf16x8*)&KBc[sw64(n0 + c, kt * 32 + 8 * g)];
                    acc = MFMA(kgr, qcur8[kt], acc);   // D: S[mt+c][n0+4g+r]
                }
#pragma unroll
                for (int r = 0; r < 4; ++r) {
                    const int e = (epack[nt] >> (8 * r)) & 0xff;
                    const float bias = (e == 1) ? eb1 : (e == 2) ? eb2 : (e == 3) ? eb3 : (e == 4) ? eb4 : eb0;
                    float sv = acc[r] * 0.125f + bias;
                    sv = (sv > 0.f) ? sv : 0.2f * sv;          // leaky BEFORE mask (ref order)
                    acc[r] = (e > 0) ? __expf(sv) : 0.f;       // masked = exact 0, no exp
                }
                sum += (acc[0] + acc[1]) + (acc[2] + acc[3]);
                const bf16x4 pg = pk4(acc[0], acc[1], acc[2], acc[3]);   // unnormalized
#pragma unroll
                for (int dt = 0; dt < 4; ++dt) {
                    const bf16x4 vgr = *(const bf16x4*)&VTc[sw128(dt * 16 + c, n0 + 4 * g)];
                    ot[dt] = MFMA16(vgr, pg, ot[dt]);
                }
            }
            // row sum across the 4 lane-groups, then normalize O~ (16 muls)
            sum += __shfl_xor(sum, 16);
            sum += __shfl_xor(sum, 32);
            const float inv = 1.f / sum;

            // ---- out-proj accumulate from normalized O granules ----
            bf16x4 ogr[4];
#pragma unroll
            for (int dt = 0; dt < 4; ++dt)
                ogr[dt] = pk4(ot[dt][0] * inv, ot[dt][1] * inv, ot[dt][2] * inv, ot[dt][3] * inv);
#pragma unroll
            for (int nt4 = 0; nt4 < 4; ++nt4) {
                const int n0 = nt4 * 16;
#pragma unroll
                for (int dt = 0; dt < 4; ++dt) {
                    const bf16x4 wgr = *(const bf16x4*)&WpT[(n0 + c) * 512 + h * 64 + dt * 16 + 4 * g];
                    projacc[nt4] = MFMA16(ogr[dt], wgr, projacc[nt4]);
                }
            }
        } else if (h < NH - 1) {
            // ---- producers: next head's K/V^T/Q into the other buffer ----
            PROJKVQ(h + 1, bufn);
        }

        // one barrier per head; the h=NH-1 barrier is dead (no LDS write after
        // the h=NH-2 barrier) — h is block-uniform, so this branch is safe.
        if (h < NH - 1) __syncthreads();
    }

    // ---- epilogue: consumers add bp and store ----
    if (cons) {
        float* og = out + (size_t)b * NM * ND;
#pragma unroll
        for (int nt4 = 0; nt4 < 4; ++nt4) {
            const int n0 = nt4 * 16;
            const float bpv = bp[n0 + c];
#pragma unroll
            for (int r = 0; r < 4; ++r)
                og[(mt + 4 * g + r) * ND + n0 + c] = projacc[nt4][r] + bpv;
        }
    }
}

extern "C" void kernel_launch(void* const* d_in, const int* in_sizes, int n_in,
                              void* d_out, int out_size, void* d_ws, size_t ws_size,
                              hipStream_t stream) {
    const float* x     = (const float*)d_in[0];
    const int*   edges = (const int*)d_in[1];
    const float* Wq    = (const float*)d_in[2];
    const float* bq    = (const float*)d_in[3];
    const float* Wk    = (const float*)d_in[4];
    const float* bk    = (const float*)d_in[5];
    const float* Wv    = (const float*)d_in[6];
    const float* bv    = (const float*)d_in[7];
    const float* eb    = (const float*)d_in[8];
    const float* Wp    = (const float*)d_in[9];
    const float* bp    = (const float*)d_in[10];
    float* out = (float*)d_out;
    ushort_t* ws = (ushort_t*)d_ws;   // needs 262144 B

    hipLaunchKernelGGL(geat_prep, dim3(512), dim3(256), 0, stream, Wq, Wk, Wv, Wp, ws);
    hipLaunchKernelGGL(geat_pc, dim3(NB), dim3(768), 0, stream,
                       x, edges, bq, bk, bv, eb, bp, ws, out);
}

// Round 23
// 99.774 us; speedup vs baseline: 1.0543x; 1.0543x over previous
//
#include <hip/hip_runtime.h>

#define NB 256
#define NM 128
#define ND 64
#define NH 8

typedef float f32x4 __attribute__((ext_vector_type(4)));
typedef short bf16x8 __attribute__((ext_vector_type(8)));   // 8 bf16 = 4 VGPRs (16x16x32 A/B)
typedef short bf16x4 __attribute__((ext_vector_type(4)));   // 4 bf16 = 2 VGPRs (16x16x16 A/B)
typedef unsigned short ushort_t;

__device__ __forceinline__ ushort_t f2bf(float f) {   // RNE f32->bf16 (prep kernel only)
    unsigned int x = __float_as_uint(f);
    x += 0x7fffu + ((x >> 16) & 1u);
    return (ushort_t)(x >> 16);
}

// v_cvt_pk_bf16_f32: 2 f32 -> 2 bf16 (RNE) in ONE VALU op (r19 win kept).
__device__ __forceinline__ unsigned cvtpk(float lo, float hi) {
    unsigned r;
    asm("v_cvt_pk_bf16_f32 %0, %1, %2" : "=v"(r) : "v"(lo), "v"(hi));
    return r;
}
__device__ __forceinline__ unsigned pk2(float a, float b) { return cvtpk(a, b); }
__device__ __forceinline__ bf16x4 pk4(float a, float b, float c, float d) {
    union { unsigned u[2]; bf16x4 v; } t;
    t.u[0] = cvtpk(a, b);
    t.u[1] = cvtpk(c, d);
    return t.v;
}
__device__ __forceinline__ bf16x8 pk8(float4 lo, float4 hi) {
    union { unsigned u[4]; bf16x8 v; } t;
    t.u[0] = cvtpk(lo.x, lo.y);
    t.u[1] = cvtpk(lo.z, lo.w);
    t.u[2] = cvtpk(hi.x, hi.y);
    t.u[3] = cvtpk(hi.z, hi.w);
    return t.v;
}

// XOR-swizzled LDS indices (T2), write and read via the SAME helper.
// XOR by multiples of 8 elems permutes 8-element blocks: b64 (4-elem aligned)
// and b128 (8-elem aligned) accesses both stay contiguous+aligned under it.
__device__ __forceinline__ int sw64(int row, int col)  { return row * 64  + (col ^ ((row & 7) << 3)); }
__device__ __forceinline__ int sw128(int row, int col) { return row * 128 + (col ^ ((row & 7) << 3)); }

__device__ __forceinline__ f32x4 MFMA(bf16x8 a, bf16x8 b, f32x4 c) {
    return __builtin_amdgcn_mfma_f32_16x16x32_bf16(a, b, c, 0, 0, 0);
}

// 16x16x16 bf16 MFMA: A/B = 4 bf16/lane (lane(c,g): row/col=c, k=4g+j).
// r22 established the _1k builtin IS available and in use (replacing it with
// zero-padded MFMA32 made things SLOWER: 100.0 -> 105.2us, +8MB spill).
#if defined(__has_builtin)
#if __has_builtin(__builtin_amdgcn_mfma_f32_16x16x16bf16_1k)
#define HAVE_MFMA16 1
__device__ __forceinline__ f32x4 MFMA16(bf16x4 a, bf16x4 b, f32x4 c) {
    return __builtin_amdgcn_mfma_f32_16x16x16bf16_1k(a, b, c, 0, 0, 0);
}
#endif
#endif
#ifndef HAVE_MFMA16
__device__ __forceinline__ f32x4 MFMA16(bf16x4 a, bf16x4 b, f32x4 c) {
    f32x4 d;
    asm volatile("v_mfma_f32_16x16x16_bf16 %0, %1, %2, %3\n\ts_nop 7\n\ts_nop 7"
                 : "=v"(d) : "v"(a), "v"(b), "v"(c));
    return d;
}
#endif

// ---- prep: transpose weights to bf16 fragment layout in d_ws ----
// ws (ushort): WqT[512][64] @0, WkT @32768, WvT @65536, WpT[64][512] @98304 (256 KB)
extern "C" __global__ void geat_prep(const float* __restrict__ Wq,
                                     const float* __restrict__ Wk,
                                     const float* __restrict__ Wv,
                                     const float* __restrict__ Wp,
                                     ushort_t* __restrict__ ws)
{
    int idx = blockIdx.x * 256 + threadIdx.x;   // 0..131071
    int seg = idx >> 15;
    int r = idx & 32767;
    float v;
    if      (seg == 0) v = Wq[(r & 63) * 512 + (r >> 6)];    // WqT[o][d] = Wq[d][o]
    else if (seg == 1) v = Wk[(r & 63) * 512 + (r >> 6)];
    else if (seg == 2) v = Wv[(r & 63) * 512 + (r >> 6)];
    else               v = Wp[(r & 511) * 64 + (r >> 9)];    // WpT[c][k] = Wp[k][c]
    ws[idx] = f2bf(v);
}

// ============================================================================
// Producer/consumer fused kernel — restored r21 best (100.0us, PASSED; the
// 99.5-100us family is the verified optimum of this structure, 130x over the
// round-2 baseline). r22's zero-padded-MFMA32 experiment REFUTED the
// asm-fallback hypothesis (builtin was active; padding added VALU+spill).
// Grid 256 (1 block/CU), 768 thr = 12 waves = 3/SIMD guaranteed (r13: blocks
// never co-schedule; r12: 1024-thr -> 64-reg cap spills; VGPR law 65536/thr).
//  - waves 0..7  consumers: 16 rows each; per head: 2 b128 Q reads, fused
//    max-free S(MFMA32)->exp->PV(MFMA16), oproj. (r15: |s|<~6 so exp can't
//    overflow; masked = exact 0; normalize O~ once at the end.)
//  - waves 8..11 producers: K/V^T/Q of head h+1 (2 tiles of 16 rows).
// LDS 96 KB: 2 x {KB 8192, VTB 8192, QB 8192} ushorts. ONE barrier per head
// (h=NH-1 barrier dead -> skipped; h is block-uniform).
// DO NOT pass a >1 min-waves launch-bounds hint (r2/r5).
// ============================================================================
extern "C" __global__ __launch_bounds__(768, 1)
void geat_pc(const float* __restrict__ x, const int* __restrict__ edges,
             const float* __restrict__ bq, const float* __restrict__ bk,
             const float* __restrict__ bv, const float* __restrict__ ebias,
             const float* __restrict__ bp, const ushort_t* __restrict__ wt,
             float* __restrict__ out)
{
    __shared__ __align__(16) ushort_t sm[49152];  // 96 KB

    const int b    = blockIdx.x;
    const int tid  = threadIdx.x;
    const int w    = tid >> 6;          // wave 0..11
    const int lane = tid & 63;
    const int c    = lane & 15;
    const int g    = lane >> 4;
    const bool cons = (w < 8);
    const int mt   = cons ? (w * 16) : ((w - 8) * 32);   // consumer rows / producer base

    const ushort_t* WqT = wt;
    const ushort_t* WkT = wt + 32768;
    const ushort_t* WvT = wt + 65536;
    const ushort_t* WpT = wt + 98304;

    // ---- persistent per-role state ----
    unsigned epack[8];     // consumers: edge codes for row mt+c (n = 16nt+4g+r)
    bf16x8   pxA[2][2];    // producers: x frags for rows mt+16*tile+c
    if (cons) {
        const int* erow = edges + (size_t)b * NM * NM + (mt + c) * NM;
#pragma unroll
        for (int nt = 0; nt < 8; ++nt) {
            const int4 e4 = *(const int4*)&erow[nt * 16 + 4 * g];
            epack[nt] = (unsigned)(e4.x & 0xff) | ((unsigned)(e4.y & 0xff) << 8) |
                        ((unsigned)(e4.z & 0xff) << 16) | ((unsigned)(e4.w & 0xff) << 24);
        }
    } else {
#pragma unroll
        for (int tile = 0; tile < 2; ++tile) {
            const float* xb = x + (size_t)b * NM * ND + (mt + tile * 16 + c) * ND;
#pragma unroll
            for (int kt = 0; kt < 2; ++kt) {
                const float4 lo = *(const float4*)&xb[kt * 32 + 8 * g];
                const float4 hi = *(const float4*)&xb[kt * 32 + 8 * g + 4];
                pxA[tile][kt] = pk8(lo, hi);
            }
        }
    }

    f32x4 projacc[4];
#pragma unroll
    for (int i = 0; i < 4; ++i) projacc[i] = (f32x4)0.0f;

    // ---- producer: K + V^T + Q of head h2 into buf (32 rows: 2 tiles) ----
    auto PROJKVQ = [&](int h2, ushort_t* buf) {
        ushort_t* KBn = buf;
        ushort_t* VTn = buf + 8192;
        ushort_t* QBn = buf + 16384;
#pragma unroll
        for (int dt = 0; dt < 4; ++dt) {
            const int d0 = dt * 16;
            bf16x8 wqf[2], wkf[2], wvf[2];
#pragma unroll
            for (int kt = 0; kt < 2; ++kt) {
                const int woff = (h2 * 64 + d0 + c) * 64 + kt * 32 + 8 * g;
                wqf[kt] = *(const bf16x8*)&WqT[woff];
                wkf[kt] = *(const bf16x8*)&WkT[woff];
                wvf[kt] = *(const bf16x8*)&WvT[woff];
            }
            const float4 bqv = *(const float4*)&bq[h2 * 64 + d0 + 4 * g];
            const float4 bkv = *(const float4*)&bk[h2 * 64 + d0 + 4 * g];
            const float  bvv = bv[h2 * 64 + d0 + c];
#pragma unroll
            for (int tile = 0; tile < 2; ++tile) {
                f32x4 qT = (f32x4)0.0f, kT = (f32x4)0.0f, vn = (f32x4)0.0f;
#pragma unroll
                for (int kt = 0; kt < 2; ++kt) {
                    qT = MFMA(wqf[kt], pxA[tile][kt], qT);   // D: Q[row+c][d0+4g+r]
                    kT = MFMA(wkf[kt], pxA[tile][kt], kT);   // D: K[row+c][d0+4g+r]
                    vn = MFMA(pxA[tile][kt], wvf[kt], vn);   // D: V[row+4g+r][d0+c]
                }
                const int rowb = mt + tile * 16;
                uint2 qp, kp, vp;
                qp.x = pk2(qT[0] + bqv.x, qT[1] + bqv.y);
                qp.y = pk2(qT[2] + bqv.z, qT[3] + bqv.w);
                kp.x = pk2(kT[0] + bkv.x, kT[1] + bkv.y);
                kp.y = pk2(kT[2] + bkv.z, kT[3] + bkv.w);
                vp.x = pk2(vn[0] + bvv, vn[1] + bvv);
                vp.y = pk2(vn[2] + bvv, vn[3] + bvv);
                *(uint2*)&QBn[sw64(rowb + c, d0 + 4 * g)] = qp;
                *(uint2*)&KBn[sw64(rowb + c, d0 + 4 * g)] = kp;
                *(uint2*)&VTn[sw128(d0 + c, rowb + 4 * g)] = vp;
            }
        }
    };

    // ---- prologue: producers fill buffer 0 with head 0's K/V^T/Q ----
    if (!cons) PROJKVQ(0, sm);
    __syncthreads();

#pragma unroll 1
    for (int h = 0; h < NH; ++h) {
        ushort_t* bufc = sm + (h & 1) * 24576;
        ushort_t* bufn = sm + ((h & 1) ^ 1) * 24576;

        if (cons) {
            ushort_t* KBc = bufc;
            ushort_t* VTc = bufc + 8192;
            ushort_t* QBc = bufc + 16384;

            // ---- own-row Q granules as two b128 reads (k = kt*32 + 8g + j) ----
            bf16x8 qcur8[2];
#pragma unroll
            for (int kt = 0; kt < 2; ++kt)
                qcur8[kt] = *(const bf16x8*)&QBc[sw64(mt + c, kt * 32 + 8 * g)];

            const float eb0 = ebias[0 * NH + h], eb1 = ebias[1 * NH + h], eb2 = ebias[2 * NH + h];
            const float eb3 = ebias[3 * NH + h], eb4 = ebias[4 * NH + h];

            // ---- fused max-free S(MFMA32) -> exp -> PV(MFMA16), one n-tile at a time ----
            f32x4 ot[4];
#pragma unroll
            for (int dt = 0; dt < 4; ++dt) ot[dt] = (f32x4)0.0f;
            float sum = 0.f;
#pragma unroll
            for (int nt = 0; nt < 8; ++nt) {
                const int n0 = nt * 16;
                f32x4 acc = (f32x4)0.0f;
#pragma unroll
                for (int kt = 0; kt < 2; ++kt) {
                    const bf16x8 kgr = *(const bf16x8*)&KBc[sw64(n0 + c, kt * 32 + 8 * g)];
                    acc = MFMA(kgr, qcur8[kt], acc);   // D: S[mt+c][n0+4g+r]
                }
#pragma unroll
                for (int r = 0; r < 4; ++r) {
                    const int e = (epack[nt] >> (8 * r)) & 0xff;
                    const float bias = (e == 1) ? eb1 : (e == 2) ? eb2 : (e == 3) ? eb3 : (e == 4) ? eb4 : eb0;
                    float sv = acc[r] * 0.125f + bias;
                    sv = (sv > 0.f) ? sv : 0.2f * sv;          // leaky BEFORE mask (ref order)
                    acc[r] = (e > 0) ? __expf(sv) : 0.f;       // masked = exact 0, no exp
                }
                sum += (acc[0] + acc[1]) + (acc[2] + acc[3]);
                const bf16x4 pg = pk4(acc[0], acc[1], acc[2], acc[3]);   // unnormalized
#pragma unroll
                for (int dt = 0; dt < 4; ++dt) {
                    const bf16x4 vgr = *(const bf16x4*)&VTc[sw128(dt * 16 + c, n0 + 4 * g)];
                    ot[dt] = MFMA16(vgr, pg, ot[dt]);
                }
            }
            // row sum across the 4 lane-groups, then normalize O~ (16 muls)
            sum += __shfl_xor(sum, 16);
            sum += __shfl_xor(sum, 32);
            const float inv = 1.f / sum;

            // ---- out-proj accumulate from normalized O granules ----
            bf16x4 ogr[4];
#pragma unroll
            for (int dt = 0; dt < 4; ++dt)
                ogr[dt] = pk4(ot[dt][0] * inv, ot[dt][1] * inv, ot[dt][2] * inv, ot[dt][3] * inv);
#pragma unroll
            for (int nt4 = 0; nt4 < 4; ++nt4) {
                const int n0 = nt4 * 16;
#pragma unroll
                for (int dt = 0; dt < 4; ++dt) {
                    const bf16x4 wgr = *(const bf16x4*)&WpT[(n0 + c) * 512 + h * 64 + dt * 16 + 4 * g];
                    projacc[nt4] = MFMA16(ogr[dt], wgr, projacc[nt4]);
                }
            }
        } else if (h < NH - 1) {
            // ---- producers: next head's K/V^T/Q into the other buffer ----
            PROJKVQ(h + 1, bufn);
        }

        // one barrier per head; the h=NH-1 barrier is dead (no LDS write after
        // the h=NH-2 barrier) — h is block-uniform, so this branch is safe.
        if (h < NH - 1) __syncthreads();
    }

    // ---- epilogue: consumers add bp and store ----
    if (cons) {
        float* og = out + (size_t)b * NM * ND;
#pragma unroll
        for (int nt4 = 0; nt4 < 4; ++nt4) {
            const int n0 = nt4 * 16;
            const float bpv = bp[n0 + c];
#pragma unroll
            for (int r = 0; r < 4; ++r)
                og[(mt + 4 * g + r) * ND + n0 + c] = projacc[nt4][r] + bpv;
        }
    }
}

extern "C" void kernel_launch(void* const* d_in, const int* in_sizes, int n_in,
                              void* d_out, int out_size, void* d_ws, size_t ws_size,
                              hipStream_t stream) {
    const float* x     = (const float*)d_in[0];
    const int*   edges = (const int*)d_in[1];
    const float* Wq    = (const float*)d_in[2];
    const float* bq    = (const float*)d_in[3];
    const float* Wk    = (const float*)d_in[4];
    const float* bk    = (const float*)d_in[5];
    const float* Wv    = (const float*)d_in[6];
    const float* bv    = (const float*)d_in[7];
    const float* eb    = (const float*)d_in[8];
    const float* Wp    = (const float*)d_in[9];
    const float* bp    = (const float*)d_in[10];
    float* out = (float*)d_out;
    ushort_t* ws = (ushort_t*)d_ws;   // needs 262144 B

    hipLaunchKernelGGL(geat_prep, dim3(512), dim3(256), 0, stream, Wq, Wk, Wv, Wp, ws);
    hipLaunchKernelGGL(geat_pc, dim3(NB), dim3(768), 0, stream,
                       x, edges, bq, bk, bv, eb, bp, ws, out);
}

// Round 24
// 86.327 us; speedup vs baseline: 1.2185x; 1.1558x over previous
//
#include <hip/hip_runtime.h>

#define NB 256
#define NM 128
#define ND 64
#define NH 8

typedef float f32x4 __attribute__((ext_vector_type(4)));
typedef short bf16x8 __attribute__((ext_vector_type(8)));   // 8 bf16 = 4 VGPRs (16x16x32 A/B)
typedef short bf16x4 __attribute__((ext_vector_type(4)));   // 4 bf16 = 2 VGPRs (16x16x16 A/B)
typedef unsigned short ushort_t;

__device__ __forceinline__ ushort_t f2bf(float f) {   // RNE f32->bf16 (prep kernel only)
    unsigned int x = __float_as_uint(f);
    x += 0x7fffu + ((x >> 16) & 1u);
    return (ushort_t)(x >> 16);
}

// v_cvt_pk_bf16_f32: 2 f32 -> 2 bf16 (RNE) in ONE VALU op (r19 win kept).
__device__ __forceinline__ unsigned cvtpk(float lo, float hi) {
    unsigned r;
    asm("v_cvt_pk_bf16_f32 %0, %1, %2" : "=v"(r) : "v"(lo), "v"(hi));
    return r;
}
__device__ __forceinline__ unsigned pk2(float a, float b) { return cvtpk(a, b); }
__device__ __forceinline__ bf16x4 pk4(float a, float b, float c, float d) {
    union { unsigned u[2]; bf16x4 v; } t;
    t.u[0] = cvtpk(a, b);
    t.u[1] = cvtpk(c, d);
    return t.v;
}
__device__ __forceinline__ bf16x8 pk8(float4 lo, float4 hi) {
    union { unsigned u[4]; bf16x8 v; } t;
    t.u[0] = cvtpk(lo.x, lo.y);
    t.u[1] = cvtpk(lo.z, lo.w);
    t.u[2] = cvtpk(hi.x, hi.y);
    t.u[3] = cvtpk(hi.z, hi.w);
    return t.v;
}

// XOR-swizzled LDS indices (T2), write and read via the SAME helper.
// XOR by multiples of 8 elems permutes 8-element blocks: b64 (4-elem aligned)
// and b128 (8-elem aligned) accesses both stay contiguous+aligned under it.
__device__ __forceinline__ int sw64(int row, int col)  { return row * 64  + (col ^ ((row & 7) << 3)); }
__device__ __forceinline__ int sw128(int row, int col) { return row * 128 + (col ^ ((row & 7) << 3)); }

__device__ __forceinline__ f32x4 MFMA(bf16x8 a, bf16x8 b, f32x4 c) {
    return __builtin_amdgcn_mfma_f32_16x16x32_bf16(a, b, c, 0, 0, 0);
}

// 16x16x16 bf16 MFMA: A/B = 4 bf16/lane (lane(c,g): row/col=c, k=4g+j).
// r22 established the _1k builtin IS available and in use (replacing it with
// zero-padded MFMA32 made things SLOWER: 100.0 -> 105.2us, +8MB spill).
#if defined(__has_builtin)
#if __has_builtin(__builtin_amdgcn_mfma_f32_16x16x16bf16_1k)
#define HAVE_MFMA16 1
__device__ __forceinline__ f32x4 MFMA16(bf16x4 a, bf16x4 b, f32x4 c) {
    return __builtin_amdgcn_mfma_f32_16x16x16bf16_1k(a, b, c, 0, 0, 0);
}
#endif
#endif
#ifndef HAVE_MFMA16
__device__ __forceinline__ f32x4 MFMA16(bf16x4 a, bf16x4 b, f32x4 c) {
    f32x4 d;
    asm volatile("v_mfma_f32_16x16x16_bf16 %0, %1, %2, %3\n\ts_nop 7\n\ts_nop 7"
                 : "=v"(d) : "v"(a), "v"(b), "v"(c));
    return d;
}
#endif

// ---- prep: transpose weights to bf16 fragment layout in d_ws ----
// ws (ushort): WqT[512][64] @0, WkT @32768, WvT @65536, WpT @98304 (256 KB)
// r24: WpT is G-MAJOR: W2[col][h][g][dt][j] = Wp[h*64 + dt*16 + 4g + j][col]
// so a lane's 4 dt-granules for (col,h,g) are 16 CONTIGUOUS ushorts -> the
// oproj reads 2 b128 per nt4 instead of 4 b64 (halves exposed load slots).
extern "C" __global__ void geat_prep(const float* __restrict__ Wq,
                                     const float* __restrict__ Wk,
                                     const float* __restrict__ Wv,
                                     const float* __restrict__ Wp,
                                     ushort_t* __restrict__ ws)
{
    int idx = blockIdx.x * 256 + threadIdx.x;   // 0..131071
    int seg = idx >> 15;
    int r = idx & 32767;
    float v;
    if      (seg == 0) v = Wq[(r & 63) * 512 + (r >> 6)];    // WqT[o][d] = Wq[d][o]
    else if (seg == 1) v = Wk[(r & 63) * 512 + (r >> 6)];
    else if (seg == 2) v = Wv[(r & 63) * 512 + (r >> 6)];
    else {                                                    // g-major WpT (see above)
        const int col = r >> 9, q = r & 511;
        const int hh  = q >> 6, gg = (q >> 4) & 3, dtt = (q >> 2) & 3, jj = q & 3;
        v = Wp[(hh * 64 + dtt * 16 + 4 * gg + jj) * 64 + col];
    }
    ws[idx] = f2bf(v);
}

// ============================================================================
// Producer/consumer fused kernel — r23 chassis (99.8us, PASSED; verified
// optimum family 99.5-100.0) + ONE change: oproj weight loads use the g-major
// WpT layout -> 8 b128/head instead of 16 b64/head (same values, same math,
// same registers; halves the oproj load-latency ladder at the 84-reg cap).
// Grid 256 (1 block/CU), 768 thr = 12 waves = 3/SIMD guaranteed (r13: blocks
// never co-schedule; r12: 1024-thr -> 64-reg cap spills; VGPR law 65536/thr).
//  - waves 0..7  consumers: 16 rows each; per head: 2 b128 Q reads, fused
//    max-free S(MFMA32)->exp->PV(MFMA16), oproj. (r15: |s|<~6 so exp can't
//    overflow; masked = exact 0; normalize O~ once at the end.)
//  - waves 8..11 producers: K/V^T/Q of head h+1 (2 tiles of 16 rows).
// LDS 96 KB: 2 x {KB 8192, VTB 8192, QB 8192} ushorts. ONE barrier per head
// (h=NH-1 barrier dead -> skipped; h is block-uniform).
// DO NOT pass a >1 min-waves launch-bounds hint (r2/r5).
// ============================================================================
extern "C" __global__ __launch_bounds__(768, 1)
void geat_pc(const float* __restrict__ x, const int* __restrict__ edges,
             const float* __restrict__ bq, const float* __restrict__ bk,
             const float* __restrict__ bv, const float* __restrict__ ebias,
             const float* __restrict__ bp, const ushort_t* __restrict__ wt,
             float* __restrict__ out)
{
    __shared__ __align__(16) ushort_t sm[49152];  // 96 KB

    const int b    = blockIdx.x;
    const int tid  = threadIdx.x;
    const int w    = tid >> 6;          // wave 0..11
    const int lane = tid & 63;
    const int c    = lane & 15;
    const int g    = lane >> 4;
    const bool cons = (w < 8);
    const int mt   = cons ? (w * 16) : ((w - 8) * 32);   // consumer rows / producer base

    const ushort_t* WqT = wt;
    const ushort_t* WkT = wt + 32768;
    const ushort_t* WvT = wt + 65536;
    const ushort_t* WpT = wt + 98304;

    // ---- persistent per-role state ----
    unsigned epack[8];     // consumers: edge codes for row mt+c (n = 16nt+4g+r)
    bf16x8   pxA[2][2];    // producers: x frags for rows mt+16*tile+c
    if (cons) {
        const int* erow = edges + (size_t)b * NM * NM + (mt + c) * NM;
#pragma unroll
        for (int nt = 0; nt < 8; ++nt) {
            const int4 e4 = *(const int4*)&erow[nt * 16 + 4 * g];
            epack[nt] = (unsigned)(e4.x & 0xff) | ((unsigned)(e4.y & 0xff) << 8) |
                        ((unsigned)(e4.z & 0xff) << 16) | ((unsigned)(e4.w & 0xff) << 24);
        }
    } else {
#pragma unroll
        for (int tile = 0; tile < 2; ++tile) {
            const float* xb = x + (size_t)b * NM * ND + (mt + tile * 16 + c) * ND;
#pragma unroll
            for (int kt = 0; kt < 2; ++kt) {
                const float4 lo = *(const float4*)&xb[kt * 32 + 8 * g];
                const float4 hi = *(const float4*)&xb[kt * 32 + 8 * g + 4];
                pxA[tile][kt] = pk8(lo, hi);
            }
        }
    }

    f32x4 projacc[4];
#pragma unroll
    for (int i = 0; i < 4; ++i) projacc[i] = (f32x4)0.0f;

    // ---- producer: K + V^T + Q of head h2 into buf (32 rows: 2 tiles) ----
    auto PROJKVQ = [&](int h2, ushort_t* buf) {
        ushort_t* KBn = buf;
        ushort_t* VTn = buf + 8192;
        ushort_t* QBn = buf + 16384;
#pragma unroll
        for (int dt = 0; dt < 4; ++dt) {
            const int d0 = dt * 16;
            bf16x8 wqf[2], wkf[2], wvf[2];
#pragma unroll
            for (int kt = 0; kt < 2; ++kt) {
                const int woff = (h2 * 64 + d0 + c) * 64 + kt * 32 + 8 * g;
                wqf[kt] = *(const bf16x8*)&WqT[woff];
                wkf[kt] = *(const bf16x8*)&WkT[woff];
                wvf[kt] = *(const bf16x8*)&WvT[woff];
            }
            const float4 bqv = *(const float4*)&bq[h2 * 64 + d0 + 4 * g];
            const float4 bkv = *(const float4*)&bk[h2 * 64 + d0 + 4 * g];
            const float  bvv = bv[h2 * 64 + d0 + c];
#pragma unroll
            for (int tile = 0; tile < 2; ++tile) {
                f32x4 qT = (f32x4)0.0f, kT = (f32x4)0.0f, vn = (f32x4)0.0f;
#pragma unroll
                for (int kt = 0; kt < 2; ++kt) {
                    qT = MFMA(wqf[kt], pxA[tile][kt], qT);   // D: Q[row+c][d0+4g+r]
                    kT = MFMA(wkf[kt], pxA[tile][kt], kT);   // D: K[row+c][d0+4g+r]
                    vn = MFMA(pxA[tile][kt], wvf[kt], vn);   // D: V[row+4g+r][d0+c]
                }
                const int rowb = mt + tile * 16;
                uint2 qp, kp, vp;
                qp.x = pk2(qT[0] + bqv.x, qT[1] + bqv.y);
                qp.y = pk2(qT[2] + bqv.z, qT[3] + bqv.w);
                kp.x = pk2(kT[0] + bkv.x, kT[1] + bkv.y);
                kp.y = pk2(kT[2] + bkv.z, kT[3] + bkv.w);
                vp.x = pk2(vn[0] + bvv, vn[1] + bvv);
                vp.y = pk2(vn[2] + bvv, vn[3] + bvv);
                *(uint2*)&QBn[sw64(rowb + c, d0 + 4 * g)] = qp;
                *(uint2*)&KBn[sw64(rowb + c, d0 + 4 * g)] = kp;
                *(uint2*)&VTn[sw128(d0 + c, rowb + 4 * g)] = vp;
            }
        }
    };

    // ---- prologue: producers fill buffer 0 with head 0's K/V^T/Q ----
    if (!cons) PROJKVQ(0, sm);
    __syncthreads();

#pragma unroll 1
    for (int h = 0; h < NH; ++h) {
        ushort_t* bufc = sm + (h & 1) * 24576;
        ushort_t* bufn = sm + ((h & 1) ^ 1) * 24576;

        if (cons) {
            ushort_t* KBc = bufc;
            ushort_t* VTc = bufc + 8192;
            ushort_t* QBc = bufc + 16384;

            // ---- own-row Q granules as two b128 reads (k = kt*32 + 8g + j) ----
            bf16x8 qcur8[2];
#pragma unroll
            for (int kt = 0; kt < 2; ++kt)
                qcur8[kt] = *(const bf16x8*)&QBc[sw64(mt + c, kt * 32 + 8 * g)];

            const float eb0 = ebias[0 * NH + h], eb1 = ebias[1 * NH + h], eb2 = ebias[2 * NH + h];
            const float eb3 = ebias[3 * NH + h], eb4 = ebias[4 * NH + h];

            // ---- fused max-free S(MFMA32) -> exp -> PV(MFMA16), one n-tile at a time ----
            f32x4 ot[4];
#pragma unroll
            for (int dt = 0; dt < 4; ++dt) ot[dt] = (f32x4)0.0f;
            float sum = 0.f;
#pragma unroll
            for (int nt = 0; nt < 8; ++nt) {
                const int n0 = nt * 16;
                f32x4 acc = (f32x4)0.0f;
#pragma unroll
                for (int kt = 0; kt < 2; ++kt) {
                    const bf16x8 kgr = *(const bf16x8*)&KBc[sw64(n0 + c, kt * 32 + 8 * g)];
                    acc = MFMA(kgr, qcur8[kt], acc);   // D: S[mt+c][n0+4g+r]
                }
#pragma unroll
                for (int r = 0; r < 4; ++r) {
                    const int e = (epack[nt] >> (8 * r)) & 0xff;
                    const float bias = (e == 1) ? eb1 : (e == 2) ? eb2 : (e == 3) ? eb3 : (e == 4) ? eb4 : eb0;
                    float sv = acc[r] * 0.125f + bias;
                    sv = (sv > 0.f) ? sv : 0.2f * sv;          // leaky BEFORE mask (ref order)
                    acc[r] = (e > 0) ? __expf(sv) : 0.f;       // masked = exact 0, no exp
                }
                sum += (acc[0] + acc[1]) + (acc[2] + acc[3]);
                const bf16x4 pg = pk4(acc[0], acc[1], acc[2], acc[3]);   // unnormalized
#pragma unroll
                for (int dt = 0; dt < 4; ++dt) {
                    const bf16x4 vgr = *(const bf16x4*)&VTc[sw128(dt * 16 + c, n0 + 4 * g)];
                    ot[dt] = MFMA16(vgr, pg, ot[dt]);
                }
            }
            // row sum across the 4 lane-groups, then normalize O~ (16 muls)
            sum += __shfl_xor(sum, 16);
            sum += __shfl_xor(sum, 32);
            const float inv = 1.f / sum;

            // ---- out-proj accumulate; g-major WpT: 2 b128 loads per nt4 ----
            bf16x4 ogr[4];
#pragma unroll
            for (int dt = 0; dt < 4; ++dt)
                ogr[dt] = pk4(ot[dt][0] * inv, ot[dt][1] * inv, ot[dt][2] * inv, ot[dt][3] * inv);
#pragma unroll
            for (int nt4 = 0; nt4 < 4; ++nt4) {
                const int n0 = nt4 * 16;
                const ushort_t* wbase = &WpT[(n0 + c) * 512 + h * 64 + g * 16];
                union { bf16x8 v; bf16x4 q[2]; } ulo, uhi;
                ulo.v = *(const bf16x8*)&wbase[0];   // dt = 0,1
                uhi.v = *(const bf16x8*)&wbase[8];   // dt = 2,3
                projacc[nt4] = MFMA16(ogr[0], ulo.q[0], projacc[nt4]);
                projacc[nt4] = MFMA16(ogr[1], ulo.q[1], projacc[nt4]);
                projacc[nt4] = MFMA16(ogr[2], uhi.q[0], projacc[nt4]);
                projacc[nt4] = MFMA16(ogr[3], uhi.q[1], projacc[nt4]);
            }
        } else if (h < NH - 1) {
            // ---- producers: next head's K/V^T/Q into the other buffer ----
            PROJKVQ(h + 1, bufn);
        }

        // one barrier per head; the h=NH-1 barrier is dead (no LDS write after
        // the h=NH-2 barrier) — h is block-uniform, so this branch is safe.
        if (h < NH - 1) __syncthreads();
    }

    // ---- epilogue: consumers add bp and store ----
    if (cons) {
        float* og = out + (size_t)b * NM * ND;
#pragma unroll
        for (int nt4 = 0; nt4 < 4; ++nt4) {
            const int n0 = nt4 * 16;
            const float bpv = bp[n0 + c];
#pragma unroll
            for (int r = 0; r < 4; ++r)
                og[(mt + 4 * g + r) * ND + n0 + c] = projacc[nt4][r] + bpv;
        }
    }
}

extern "C" void kernel_launch(void* const* d_in, const int* in_sizes, int n_in,
                              void* d_out, int out_size, void* d_ws, size_t ws_size,
                              hipStream_t stream) {
    const float* x     = (const float*)d_in[0];
    const int*   edges = (const int*)d_in[1];
    const float* Wq    = (const float*)d_in[2];
    const float* bq    = (const float*)d_in[3];
    const float* Wk    = (const float*)d_in[4];
    const float* bk    = (const float*)d_in[5];
    const float* Wv    = (const float*)d_in[6];
    const float* bv    = (const float*)d_in[7];
    const float* eb    = (const float*)d_in[8];
    const float* Wp    = (const float*)d_in[9];
    const float* bp    = (const float*)d_in[10];
    float* out = (float*)d_out;
    ushort_t* ws = (ushort_t*)d_ws;   // needs 262144 B

    hipLaunchKernelGGL(geat_prep, dim3(512), dim3(256), 0, stream, Wq, Wk, Wv, Wp, ws);
    hipLaunchKernelGGL(geat_pc, dim3(NB), dim3(768), 0, stream,
                       x, edges, bq, bk, bv, eb, bp, ws, out);
}

// Round 26
// 86.327 us; speedup vs baseline: 1.2185x; 1.0000x over previous
//
#include <hip/hip_runtime.h>

#define NB 256
#define NM 128
#define ND 64
#define NH 8

typedef float f32x4 __attribute__((ext_vector_type(4)));
typedef short bf16x8 __attribute__((ext_vector_type(8)));   // 8 bf16 = 4 VGPRs (16x16x32 A/B)
typedef short bf16x4 __attribute__((ext_vector_type(4)));   // 4 bf16 = 2 VGPRs (16x16x16 A/B)
typedef unsigned short ushort_t;

__device__ __forceinline__ ushort_t f2bf(float f) {   // RNE f32->bf16 (prep kernel only)
    unsigned int x = __float_as_uint(f);
    x += 0x7fffu + ((x >> 16) & 1u);
    return (ushort_t)(x >> 16);
}

// v_cvt_pk_bf16_f32: 2 f32 -> 2 bf16 (RNE) in ONE VALU op (r19 win kept).
__device__ __forceinline__ unsigned cvtpk(float lo, float hi) {
    unsigned r;
    asm("v_cvt_pk_bf16_f32 %0, %1, %2" : "=v"(r) : "v"(lo), "v"(hi));
    return r;
}
__device__ __forceinline__ unsigned pk2(float a, float b) { return cvtpk(a, b); }
__device__ __forceinline__ bf16x4 pk4(float a, float b, float c, float d) {
    union { unsigned u[2]; bf16x4 v; } t;
    t.u[0] = cvtpk(a, b);
    t.u[1] = cvtpk(c, d);
    return t.v;
}
__device__ __forceinline__ bf16x8 pk8(float4 lo, float4 hi) {
    union { unsigned u[4]; bf16x8 v; } t;
    t.u[0] = cvtpk(lo.x, lo.y);
    t.u[1] = cvtpk(lo.z, lo.w);
    t.u[2] = cvtpk(hi.x, hi.y);
    t.u[3] = cvtpk(hi.z, hi.w);
    return t.v;
}

// XOR-swizzled LDS indices (T2), write and read via the SAME helper.
// XOR by multiples of 8 elems permutes 8-element blocks: b64 (4-elem aligned)
// and b128 (8-elem aligned) accesses both stay contiguous+aligned under it.
__device__ __forceinline__ int sw64(int row, int col)  { return row * 64  + (col ^ ((row & 7) << 3)); }
__device__ __forceinline__ int sw128(int row, int col) { return row * 128 + (col ^ ((row & 7) << 3)); }

__device__ __forceinline__ f32x4 MFMA(bf16x8 a, bf16x8 b, f32x4 c) {
    return __builtin_amdgcn_mfma_f32_16x16x32_bf16(a, b, c, 0, 0, 0);
}

// 16x16x16 bf16 MFMA: A/B = 4 bf16/lane (lane(c,g): row/col=c, k=4g+j).
// r22 established the _1k builtin IS available and in use (replacing it with
// zero-padded MFMA32 made things SLOWER: 100.0 -> 105.2us, +8MB spill).
#if defined(__has_builtin)
#if __has_builtin(__builtin_amdgcn_mfma_f32_16x16x16bf16_1k)
#define HAVE_MFMA16 1
__device__ __forceinline__ f32x4 MFMA16(bf16x4 a, bf16x4 b, f32x4 c) {
    return __builtin_amdgcn_mfma_f32_16x16x16bf16_1k(a, b, c, 0, 0, 0);
}
#endif
#endif
#ifndef HAVE_MFMA16
__device__ __forceinline__ f32x4 MFMA16(bf16x4 a, bf16x4 b, f32x4 c) {
    f32x4 d;
    asm volatile("v_mfma_f32_16x16x16_bf16 %0, %1, %2, %3\n\ts_nop 7\n\ts_nop 7"
                 : "=v"(d) : "v"(a), "v"(b), "v"(c));
    return d;
}
#endif

// ---- prep: transpose weights to bf16 fragment layout in d_ws ----
// ws (ushort): WqT[512][64] @0, WkT @32768, WvT @65536, WpT @98304 (256 KB)
// r24: WpT is G-MAJOR: W2[col][h][g][dt][j] = Wp[h*64 + dt*16 + 4g + j][col]
// so a lane's 4 dt-granules for (col,h,g) are 16 CONTIGUOUS ushorts -> the
// oproj reads 2 b128 per nt4 instead of 4 b64 (halves exposed load slots).
extern "C" __global__ void geat_prep(const float* __restrict__ Wq,
                                     const float* __restrict__ Wk,
                                     const float* __restrict__ Wv,
                                     const float* __restrict__ Wp,
                                     ushort_t* __restrict__ ws)
{
    int idx = blockIdx.x * 256 + threadIdx.x;   // 0..131071
    int seg = idx >> 15;
    int r = idx & 32767;
    float v;
    if      (seg == 0) v = Wq[(r & 63) * 512 + (r >> 6)];    // WqT[o][d] = Wq[d][o]
    else if (seg == 1) v = Wk[(r & 63) * 512 + (r >> 6)];
    else if (seg == 2) v = Wv[(r & 63) * 512 + (r >> 6)];
    else {                                                    // g-major WpT (see above)
        const int col = r >> 9, q = r & 511;
        const int hh  = q >> 6, gg = (q >> 4) & 3, dtt = (q >> 2) & 3, jj = q & 3;
        v = Wp[(hh * 64 + dtt * 16 + 4 * gg + jj) * 64 + col];
    }
    ws[idx] = f2bf(v);
}

// ============================================================================
// Producer/consumer fused kernel — r24 VERIFIED BEST (86.3us, PASSED; 151x
// over the 13031us round-2 baseline). r25's Wp-through-LDS attempt FAILED
// correctness with source-level-equivalent math — second unexplained failure
// from modifying the producer lambda (after r20); that line is closed.
// Grid 256 (1 block/CU), 768 thr = 12 waves = 3/SIMD guaranteed (r13: blocks
// never co-schedule; r12: 1024-thr -> 64-reg cap spills; VGPR law 65536/thr).
//  - waves 0..7  consumers: 16 rows each; per head: 2 b128 Q reads, fused
//    max-free S(MFMA32)->exp->PV(MFMA16), oproj via g-major WpT (2 b128/nt4).
//    (r15: |s|<~6 so exp can't overflow; masked = exact 0; normalize O~ once.)
//  - waves 8..11 producers: K/V^T/Q of head h+1 (2 tiles of 16 rows).
// LDS 96 KB: 2 x {KB 8192, VTB 8192, QB 8192} ushorts. ONE barrier per head
// (h=NH-1 barrier dead -> skipped; h is block-uniform).
// DO NOT pass a >1 min-waves launch-bounds hint (r2/r5).
// ============================================================================
extern "C" __global__ __launch_bounds__(768, 1)
void geat_pc(const float* __restrict__ x, const int* __restrict__ edges,
             const float* __restrict__ bq, const float* __restrict__ bk,
             const float* __restrict__ bv, const float* __restrict__ ebias,
             const float* __restrict__ bp, const ushort_t* __restrict__ wt,
             float* __restrict__ out)
{
    __shared__ __align__(16) ushort_t sm[49152];  // 96 KB

    const int b    = blockIdx.x;
    const int tid  = threadIdx.x;
    const int w    = tid >> 6;          // wave 0..11
    const int lane = tid & 63;
    const int c    = lane & 15;
    const int g    = lane >> 4;
    const bool cons = (w < 8);
    const int mt   = cons ? (w * 16) : ((w - 8) * 32);   // consumer rows / producer base

    const ushort_t* WqT = wt;
    const ushort_t* WkT = wt + 32768;
    const ushort_t* WvT = wt + 65536;
    const ushort_t* WpT = wt + 98304;

    // ---- persistent per-role state ----
    unsigned epack[8];     // consumers: edge codes for row mt+c (n = 16nt+4g+r)
    bf16x8   pxA[2][2];    // producers: x frags for rows mt+16*tile+c
    if (cons) {
        const int* erow = edges + (size_t)b * NM * NM + (mt + c) * NM;
#pragma unroll
        for (int nt = 0; nt < 8; ++nt) {
            const int4 e4 = *(const int4*)&erow[nt * 16 + 4 * g];
            epack[nt] = (unsigned)(e4.x & 0xff) | ((unsigned)(e4.y & 0xff) << 8) |
                        ((unsigned)(e4.z & 0xff) << 16) | ((unsigned)(e4.w & 0xff) << 24);
        }
    } else {
#pragma unroll
        for (int tile = 0; tile < 2; ++tile) {
            const float* xb = x + (size_t)b * NM * ND + (mt + tile * 16 + c) * ND;
#pragma unroll
            for (int kt = 0; kt < 2; ++kt) {
                const float4 lo = *(const float4*)&xb[kt * 32 + 8 * g];
                const float4 hi = *(const float4*)&xb[kt * 32 + 8 * g + 4];
                pxA[tile][kt] = pk8(lo, hi);
            }
        }
    }

    f32x4 projacc[4];
#pragma unroll
    for (int i = 0; i < 4; ++i) projacc[i] = (f32x4)0.0f;

    // ---- producer: K + V^T + Q of head h2 into buf (32 rows: 2 tiles) ----
    auto PROJKVQ = [&](int h2, ushort_t* buf) {
        ushort_t* KBn = buf;
        ushort_t* VTn = buf + 8192;
        ushort_t* QBn = buf + 16384;
#pragma unroll
        for (int dt = 0; dt < 4; ++dt) {
            const int d0 = dt * 16;
            bf16x8 wqf[2], wkf[2], wvf[2];
#pragma unroll
            for (int kt = 0; kt < 2; ++kt) {
                const int woff = (h2 * 64 + d0 + c) * 64 + kt * 32 + 8 * g;
                wqf[kt] = *(const bf16x8*)&WqT[woff];
                wkf[kt] = *(const bf16x8*)&WkT[woff];
                wvf[kt] = *(const bf16x8*)&WvT[woff];
            }
            const float4 bqv = *(const float4*)&bq[h2 * 64 + d0 + 4 * g];
            const float4 bkv = *(const float4*)&bk[h2 * 64 + d0 + 4 * g];
            const float  bvv = bv[h2 * 64 + d0 + c];
#pragma unroll
            for (int tile = 0; tile < 2; ++tile) {
                f32x4 qT = (f32x4)0.0f, kT = (f32x4)0.0f, vn = (f32x4)0.0f;
#pragma unroll
                for (int kt = 0; kt < 2; ++kt) {
                    qT = MFMA(wqf[kt], pxA[tile][kt], qT);   // D: Q[row+c][d0+4g+r]
                    kT = MFMA(wkf[kt], pxA[tile][kt], kT);   // D: K[row+c][d0+4g+r]
                    vn = MFMA(pxA[tile][kt], wvf[kt], vn);   // D: V[row+4g+r][d0+c]
                }
                const int rowb = mt + tile * 16;
                uint2 qp, kp, vp;
                qp.x = pk2(qT[0] + bqv.x, qT[1] + bqv.y);
                qp.y = pk2(qT[2] + bqv.z, qT[3] + bqv.w);
                kp.x = pk2(kT[0] + bkv.x, kT[1] + bkv.y);
                kp.y = pk2(kT[2] + bkv.z, kT[3] + bkv.w);
                vp.x = pk2(vn[0] + bvv, vn[1] + bvv);
                vp.y = pk2(vn[2] + bvv, vn[3] + bvv);
                *(uint2*)&QBn[sw64(rowb + c, d0 + 4 * g)] = qp;
                *(uint2*)&KBn[sw64(rowb + c, d0 + 4 * g)] = kp;
                *(uint2*)&VTn[sw128(d0 + c, rowb + 4 * g)] = vp;
            }
        }
    };

    // ---- prologue: producers fill buffer 0 with head 0's K/V^T/Q ----
    if (!cons) PROJKVQ(0, sm);
    __syncthreads();

#pragma unroll 1
    for (int h = 0; h < NH; ++h) {
        ushort_t* bufc = sm + (h & 1) * 24576;
        ushort_t* bufn = sm + ((h & 1) ^ 1) * 24576;

        if (cons) {
            ushort_t* KBc = bufc;
            ushort_t* VTc = bufc + 8192;
            ushort_t* QBc = bufc + 16384;

            // ---- own-row Q granules as two b128 reads (k = kt*32 + 8g + j) ----
            bf16x8 qcur8[2];
#pragma unroll
            for (int kt = 0; kt < 2; ++kt)
                qcur8[kt] = *(const bf16x8*)&QBc[sw64(mt + c, kt * 32 + 8 * g)];

            const float eb0 = ebias[0 * NH + h], eb1 = ebias[1 * NH + h], eb2 = ebias[2 * NH + h];
            const float eb3 = ebias[3 * NH + h], eb4 = ebias[4 * NH + h];

            // ---- fused max-free S(MFMA32) -> exp -> PV(MFMA16), one n-tile at a time ----
            f32x4 ot[4];
#pragma unroll
            for (int dt = 0; dt < 4; ++dt) ot[dt] = (f32x4)0.0f;
            float sum = 0.f;
#pragma unroll
            for (int nt = 0; nt < 8; ++nt) {
                const int n0 = nt * 16;
                f32x4 acc = (f32x4)0.0f;
#pragma unroll
                for (int kt = 0; kt < 2; ++kt) {
                    const bf16x8 kgr = *(const bf16x8*)&KBc[sw64(n0 + c, kt * 32 + 8 * g)];
                    acc = MFMA(kgr, qcur8[kt], acc);   // D: S[mt+c][n0+4g+r]
                }
#pragma unroll
                for (int r = 0; r < 4; ++r) {
                    const int e = (epack[nt] >> (8 * r)) & 0xff;
                    const float bias = (e == 1) ? eb1 : (e == 2) ? eb2 : (e == 3) ? eb3 : (e == 4) ? eb4 : eb0;
                    float sv = acc[r] * 0.125f + bias;
                    sv = (sv > 0.f) ? sv : 0.2f * sv;          // leaky BEFORE mask (ref order)
                    acc[r] = (e > 0) ? __expf(sv) : 0.f;       // masked = exact 0, no exp
                }
                sum += (acc[0] + acc[1]) + (acc[2] + acc[3]);
                const bf16x4 pg = pk4(acc[0], acc[1], acc[2], acc[3]);   // unnormalized
#pragma unroll
                for (int dt = 0; dt < 4; ++dt) {
                    const bf16x4 vgr = *(const bf16x4*)&VTc[sw128(dt * 16 + c, n0 + 4 * g)];
                    ot[dt] = MFMA16(vgr, pg, ot[dt]);
                }
            }
            // row sum across the 4 lane-groups, then normalize O~ (16 muls)
            sum += __shfl_xor(sum, 16);
            sum += __shfl_xor(sum, 32);
            const float inv = 1.f / sum;

            // ---- out-proj accumulate; g-major WpT: 2 b128 loads per nt4 ----
            bf16x4 ogr[4];
#pragma unroll
            for (int dt = 0; dt < 4; ++dt)
                ogr[dt] = pk4(ot[dt][0] * inv, ot[dt][1] * inv, ot[dt][2] * inv, ot[dt][3] * inv);
#pragma unroll
            for (int nt4 = 0; nt4 < 4; ++nt4) {
                const int n0 = nt4 * 16;
                const ushort_t* wbase = &WpT[(n0 + c) * 512 + h * 64 + g * 16];
                union { bf16x8 v; bf16x4 q[2]; } ulo, uhi;
                ulo.v = *(const bf16x8*)&wbase[0];   // dt = 0,1
                uhi.v = *(const bf16x8*)&wbase[8];   // dt = 2,3
                projacc[nt4] = MFMA16(ogr[0], ulo.q[0], projacc[nt4]);
                projacc[nt4] = MFMA16(ogr[1], ulo.q[1], projacc[nt4]);
                projacc[nt4] = MFMA16(ogr[2], uhi.q[0], projacc[nt4]);
                projacc[nt4] = MFMA16(ogr[3], uhi.q[1], projacc[nt4]);
            }
        } else if (h < NH - 1) {
            // ---- producers: next head's K/V^T/Q into the other buffer ----
            PROJKVQ(h + 1, bufn);
        }

        // one barrier per head; the h=NH-1 barrier is dead (no LDS write after
        // the h=NH-2 barrier) — h is block-uniform, so this branch is safe.
        if (h < NH - 1) __syncthreads();
    }

    // ---- epilogue: consumers add bp and store ----
    if (cons) {
        float* og = out + (size_t)b * NM * ND;
#pragma unroll
        for (int nt4 = 0; nt4 < 4; ++nt4) {
            const int n0 = nt4 * 16;
            const float bpv = bp[n0 + c];
#pragma unroll
            for (int r = 0; r < 4; ++r)
                og[(mt + 4 * g + r) * ND + n0 + c] = projacc[nt4][r] + bpv;
        }
    }
}

extern "C" void kernel_launch(void* const* d_in, const int* in_sizes, int n_in,
                              void* d_out, int out_size, void* d_ws, size_t ws_size,
                              hipStream_t stream) {
    const float* x     = (const float*)d_in[0];
    const int*   edges = (const int*)d_in[1];
    const float* Wq    = (const float*)d_in[2];
    const float* bq    = (const float*)d_in[3];
    const float* Wk    = (const float*)d_in[4];
    const float* bk    = (const float*)d_in[5];
    const float* Wv    = (const float*)d_in[6];
    const float* bv    = (const float*)d_in[7];
    const float* eb    = (const float*)d_in[8];
    const float* Wp    = (const float*)d_in[9];
    const float* bp    = (const float*)d_in[10];
    float* out = (float*)d_out;
    ushort_t* ws = (ushort_t*)d_ws;   // needs 262144 B

    hipLaunchKernelGGL(geat_prep, dim3(512), dim3(256), 0, stream, Wq, Wk, Wv, Wp, ws);
    hipLaunchKernelGGL(geat_pc, dim3(NB), dim3(768), 0, stream,
                       x, edges, bq, bk, bv, eb, bp, ws, out);
}